// Round 4
// baseline (248.642 us; speedup 1.0000x reference)
//
#include <hip/hip_runtime.h>

#define W      512
#define NSTEP  100
#define OUTH   30                  // output rows per tile
#define RROWS  32                  // rasterized rows = OUTH + 2 halo
#define NTILE  18                  // ceil(512 / OUTH)
#define CSTR   516                 // LDS row stride (cols -1..512 at 0..513, padded)

__global__ __launch_bounds__(256) void qbc_kernel(
    const float* __restrict__ strokes, float* __restrict__ out, int B)
{
    #pragma clang fp contract(off)   // match XLA per-op IEEE fp32 for the predicate

    const int b   = blockIdx.y;
    const int R0  = blockIdx.x * OUTH;   // output rows R0..R0+OUTH-1
    const int tid = threadIdx.x;

    __shared__ float4 steps[NSTEP];
    __shared__ float4 clist[NSTEP];
    __shared__ int    flags[NSTEP];
    __shared__ int    nlist;
    __shared__ __align__(16) float canvas[RROWS * CSTR];

    // ---- zero canvas (all threads; overlaps with Phase A) ----
    {
        float4 z = make_float4(0.f, 0.f, 0.f, 0.f);
        float4* cz = (float4*)canvas;
        const int nv = (RROWS * CSTR) / 4;           // 4128
        for (int i = tid; i < nv; i += 256) cz[i] = z;
    }

    // ---- Phase A: per-step params (bit-exact mirror of reference fp32 ops) ----
    if (tid < NSTEP) {
        const float* s = strokes + b * 10;
        float P0x = s[0], P0y = s[1];
        float m1x = s[2], m1y = s[3];
        float P2x = s[4], P2y = s[5];
        float P1x = P0x + (P2x - P0x) * m1x;
        float P1y = P0y + (P2y - P0y) * m1y;
        float X0 = P0x * 511.0f + 0.5f;
        float X1 = P1x * 511.0f + 0.5f;
        float X2 = P2x * 511.0f + 0.5f;
        float Y0 = P0y * 511.0f + 0.5f;
        float Y1 = P1y * 511.0f + 0.5f;
        float Y2 = P2y * 511.0f + 0.5f;
        float r0 = 1.0f + s[6] * 128.0f;
        float r2 = 1.0f + s[7] * 128.0f;
        float c0 = s[8], c2 = s[9];
        float tf = (float)tid * (1.0f / 99.0f);      // jnp.linspace fp32 semantics
        float mt = 1.0f - tf;
        float s0 = mt * mt;
        float s1 = (2.0f * mt) * tf;
        float s2 = tf * tf;
        float ex0 = X0 * s0, ex1 = X1 * s1, ex2 = X2 * s2;
        float X   = (ex0 + ex1) + ex2;
        float ey0 = Y0 * s0, ey1 = Y1 * s1, ey2 = Y2 * s2;
        float Y   = (ey0 + ey1) + ey2;
        float ra  = r0 * mt, rb = r2 * tf;
        float rt  = ra + rb;
        float r2t = rt * rt;
        float ca  = c0 * mt, cb = c2 * tf;
        float ct  = ca + cb;
        steps[tid] = make_float4(X, Y, r2t, ct);

        // cull vs raster row window [R0-1, R0+OUTH] (margin 4 >> fp slop)
        float lo_i = (float)(R0 - 1), hi_i = (float)(R0 + OUTH);
        float ci = fminf(fmaxf(X, lo_i), hi_i);
        float di = X - ci;
        flags[tid] = ((di * di) < (r2t + 4.0f)) ? 1 : 0;
    }
    __syncthreads();

    // ---- Phase B: order-preserving compaction (wave 0, ballot prefix) ----
    if (tid < 64) {
        bool f0 = flags[tid] != 0;
        unsigned long long m0 = __ballot(f0);
        int p0 = __popcll(m0 & ((1ull << tid) - 1ull));
        if (f0) clist[p0] = steps[tid];
        int cnt = __popcll(m0);
        int t1 = 64 + tid;
        bool f1 = (t1 < NSTEP) && (flags[t1] != 0);
        unsigned long long m1 = __ballot(f1);
        int p1 = __popcll(m1 & ((1ull << tid) - 1ull));
        if (f1) clist[cnt + p1] = steps[t1];
        if (tid == 0) nlist = cnt + __popcll(m1);
    }

    // thread layout: wave-coherent 8-row slabs
    const int seg = tid & 7;             // 64-col segment
    const int row = tid >> 3;            // local raster row 0..31
    const int gi  = R0 - 1 + row;        // global row
    const float fi = (float)gi;
    const int  c0i = seg * 64;
    const float c0f = (float)c0i, c1f = (float)(c0i + 63);
    float* crow = &canvas[row * CSTR + 1];   // col j at crow[j]

    __syncthreads();
    const int n = nlist;

    // ---- Phase C: backward interval rasterization with undone mask ----
    unsigned long long undone = (gi >= 0 && gi < W) ? ~0ull : 0ull;

    for (int k = n - 1; k >= 0; --k) {
        if (__all(undone == 0ull)) break;          // uniform early exit
        if (!undone) continue;                     // lane-level skip
        float4 st = clist[k];                      // X, Y, r2, color (broadcast)
        float X = st.x, Y = st.y, r2 = st.z;

        // combined row+segment cull (conservative, margin 4 >> fp slop)
        float cy  = fminf(fmaxf(Y, c0f), c1f);
        float dyc = Y - cy;
        float dx  = fi - X;
        float dxq = dx * dx;                       // exact fp32, reused by predicate
        if (dyc * dyc + dxq >= r2 + 4.0f) continue;

        float T = r2 - dxq;
        if (T < -0.375f) continue;

        // exact fp32 predicate (bit-identical to reference)
        auto ehit = [&](int j) -> bool {
            float dy  = (float)j - Y;
            float dyq = dy * dy;
            float d2  = dxq + dyq;
            return d2 < r2;
        };

        float s_in = (T > 0.375f) ? sqrtf(T - 0.375f) : 0.0f;
        int gl = (int)ceilf (Y - s_in);
        int gh = (int)floorf(Y + s_in);

        int jlo, jhi;
        if (gh - gl >= 4) {
            // boundary provably in {gl-1, gl, gl+1} / {gh-1, gh, gh+1}
            jlo = ehit(gl - 1) ? gl - 1 : (ehit(gl) ? gl : gl + 1);
            jhi = ehit(gh + 1) ? gh + 1 : (ehit(gh) ? gh : gh - 1);
        } else {
            // tiny/tangent interval: exact-test the whole candidate window
            jlo = 1; jhi = 0;
            for (int j = gl - 1; j <= gh + 1; ++j) {
                if (ehit(j)) { if (jlo > jhi) jlo = j; jhi = j; }
            }
            if (jlo > jhi) continue;
        }

        int lo = jlo > c0i ? jlo : c0i;
        int hi = jhi < c0i + 63 ? jhi : c0i + 63;
        if (lo > hi) continue;
        int bl = lo - c0i, bh = hi - c0i;
        unsigned long long m = (~0ull >> (63 - bh)) & (~0ull << bl);
        unsigned long long paint = m & undone;
        undone &= ~m;
        float col = st.w;
        while (paint) {
            int j = __builtin_ctzll(paint);
            paint &= paint - 1;
            crow[c0i + j] = col;
        }
    }
    __syncthreads();

    // ---- Phase D: separable sliding 3x3 blur + (1 - x), coalesced float2 store ----
    const float A    = 0.13533528323661270f;                  // e^-2
    const double Ad  = 0.13533528323661270;
    const float INVS = (float)(1.0 / ((1.0 + 2.0 * Ad) * (1.0 + 2.0 * Ad)));

    const int j0 = tid << 1;                                  // 0..510
    auto hrow = [&](int rr) -> float2 {
        const float* p = &canvas[rr * CSTR + j0];             // p[0] = col j0-1
        float x0 = p[0], x1 = p[1], x2 = p[2], x3 = p[3];
        return make_float2(x1 + A * (x0 + x2), x2 + A * (x1 + x3));
    };

    float2 hp = hrow(0);
    float2 hm = hrow(1);
    for (int orow = 0; orow < OUTH; ++orow) {
        float2 hn = hrow(orow + 2);
        int grow = R0 + orow;
        if (grow < W) {
            float2 o;
            o.x = 1.0f - (hm.x + A * (hp.x + hn.x)) * INVS;
            o.y = 1.0f - (hm.y + A * (hp.y + hn.y)) * INVS;
            *reinterpret_cast<float2*>(&out[((size_t)b * W + grow) * W + j0]) = o;
        }
        hp = hm; hm = hn;
    }
}

extern "C" void kernel_launch(void* const* d_in, const int* in_sizes, int n_in,
                              void* d_out, int out_size, void* d_ws, size_t ws_size,
                              hipStream_t stream) {
    const float* strokes = (const float*)d_in[0];
    float* out = (float*)d_out;
    int B = in_sizes[0] / 10;
    dim3 grid(NTILE, B);
    qbc_kernel<<<grid, dim3(256), 0, stream>>>(strokes, out, B);
}

// Round 5
// 233.378 us; speedup vs baseline: 1.0654x; 1.0654x over previous
//
#include <hip/hip_runtime.h>

#define W      512
#define NSTEP  100
#define OUTH   14                  // output rows per tile
#define RROWS  16                  // rasterized rows = OUTH + 2 halo
#define NTILE  37                  // ceil(512 / OUTH)
#define CSTR   516                 // LDS row stride (cols -1..512 at 0..513, padded)
#define SEGW   32                  // columns per thread segment

__global__ __launch_bounds__(256) void qbc_kernel(
    const float* __restrict__ strokes, float* __restrict__ out, int B)
{
    #pragma clang fp contract(off)   // match XLA per-op IEEE fp32 for the predicate

    const int b   = blockIdx.y;
    const int R0  = blockIdx.x * OUTH;   // output rows R0..R0+OUTH-1
    const int tid = threadIdx.x;

    __shared__ float4 steps[NSTEP];
    __shared__ float4 clist[NSTEP];
    __shared__ int    flags[NSTEP];
    __shared__ int    nlist;
    __shared__ __align__(16) float canvas[RROWS * CSTR];

    // ---- zero canvas (all threads; overlaps with Phase A) ----
    {
        float4 z = make_float4(0.f, 0.f, 0.f, 0.f);
        float4* cz = (float4*)canvas;
        const int nv = (RROWS * CSTR) / 4;           // 2064
        for (int i = tid; i < nv; i += 256) cz[i] = z;
    }

    // ---- Phase A: per-step params (bit-exact mirror of reference fp32 ops) ----
    if (tid < NSTEP) {
        const float* s = strokes + b * 10;
        float P0x = s[0], P0y = s[1];
        float m1x = s[2], m1y = s[3];
        float P2x = s[4], P2y = s[5];
        float P1x = P0x + (P2x - P0x) * m1x;
        float P1y = P0y + (P2y - P0y) * m1y;
        float X0 = P0x * 511.0f + 0.5f;
        float X1 = P1x * 511.0f + 0.5f;
        float X2 = P2x * 511.0f + 0.5f;
        float Y0 = P0y * 511.0f + 0.5f;
        float Y1 = P1y * 511.0f + 0.5f;
        float Y2 = P2y * 511.0f + 0.5f;
        float r0 = 1.0f + s[6] * 128.0f;
        float r2 = 1.0f + s[7] * 128.0f;
        float c0 = s[8], c2 = s[9];
        float tf = (float)tid * (1.0f / 99.0f);      // jnp.linspace fp32 semantics
        float mt = 1.0f - tf;
        float s0 = mt * mt;
        float s1 = (2.0f * mt) * tf;
        float s2 = tf * tf;
        float ex0 = X0 * s0, ex1 = X1 * s1, ex2 = X2 * s2;
        float X   = (ex0 + ex1) + ex2;
        float ey0 = Y0 * s0, ey1 = Y1 * s1, ey2 = Y2 * s2;
        float Y   = (ey0 + ey1) + ey2;
        float ra  = r0 * mt, rb = r2 * tf;
        float rt  = ra + rb;
        float r2t = rt * rt;
        float ca  = c0 * mt, cb = c2 * tf;
        float ct  = ca + cb;
        steps[tid] = make_float4(X, Y, r2t, ct);

        // cull vs raster row window [R0-1, R0+OUTH] (margin 4 >> fp slop)
        float lo_i = (float)(R0 - 1), hi_i = (float)(R0 + OUTH);
        float ci = fminf(fmaxf(X, lo_i), hi_i);
        float di = X - ci;
        flags[tid] = ((di * di) < (r2t + 4.0f)) ? 1 : 0;
    }
    __syncthreads();

    // ---- Phase B: order-preserving compaction (wave 0, ballot prefix) ----
    if (tid < 64) {
        bool f0 = flags[tid] != 0;
        unsigned long long m0 = __ballot(f0);
        int p0 = __popcll(m0 & ((1ull << tid) - 1ull));
        if (f0) clist[p0] = steps[tid];
        int cnt = __popcll(m0);
        int t1 = 64 + tid;
        bool f1 = (t1 < NSTEP) && (flags[t1] != 0);
        unsigned long long m1 = __ballot(f1);
        int p1 = __popcll(m1 & ((1ull << tid) - 1ull));
        if (f1) clist[cnt + p1] = steps[t1];
        if (tid == 0) nlist = cnt + __popcll(m1);
    }

    // thread layout: 16 rows x 16 segments of 32 cols; wave = 4 adjacent rows
    const int seg = tid & 15;            // 32-col segment
    const int row = tid >> 4;            // local raster row 0..15
    const int gi  = R0 - 1 + row;        // global row
    const float fi = (float)gi;
    const int  c0i = seg * SEGW;
    const float c0f = (float)c0i, c1f = (float)(c0i + SEGW - 1);
    float* crow = &canvas[row * CSTR + 1];   // col j at crow[j]

    __syncthreads();
    const int n = nlist;

    // ---- Phase C: backward interval rasterization with undone mask ----
    unsigned int undone = (gi >= 0 && gi < W) ? ~0u : 0u;

    for (int k = n - 1; k >= 0; --k) {
        if (__all(undone == 0u)) break;            // uniform early exit
        if (!undone) continue;                     // lane-level skip
        float4 st = clist[k];                      // X, Y, r2, color (broadcast)
        float X = st.x, Y = st.y, r2 = st.z;

        // combined row+segment cull (conservative, margin 4 >> fp slop)
        float cy  = fminf(fmaxf(Y, c0f), c1f);
        float dyc = Y - cy;
        float dx  = fi - X;
        float dxq = dx * dx;                       // exact fp32, reused by predicate
        if (dyc * dyc + dxq >= r2 + 4.0f) continue;

        float T = r2 - dxq;
        if (T < -0.375f) continue;

        // exact fp32 predicate (bit-identical to reference)
        auto ehit = [&](int j) -> bool {
            float dy  = (float)j - Y;
            float dyq = dy * dy;
            float d2  = dxq + dyq;
            return d2 < r2;
        };

        float s_in = (T > 0.375f) ? sqrtf(T - 0.375f) : 0.0f;
        int gl = (int)ceilf (Y - s_in);
        int gh = (int)floorf(Y + s_in);

        int jlo, jhi;
        if (gh - gl >= 4) {
            // boundary provably in {gl-1, gl, gl+1} / {gh-1, gh, gh+1}
            jlo = ehit(gl - 1) ? gl - 1 : (ehit(gl) ? gl : gl + 1);
            jhi = ehit(gh + 1) ? gh + 1 : (ehit(gh) ? gh : gh - 1);
        } else {
            // tiny/tangent interval: exact-test the whole candidate window
            jlo = 1; jhi = 0;
            for (int j = gl - 1; j <= gh + 1; ++j) {
                if (ehit(j)) { if (jlo > jhi) jlo = j; jhi = j; }
            }
            if (jlo > jhi) continue;
        }

        int lo = jlo > c0i ? jlo : c0i;
        int hi = jhi < c0i + SEGW - 1 ? jhi : c0i + SEGW - 1;
        if (lo > hi) continue;
        int bl = lo - c0i, bh = hi - c0i;
        unsigned int m = (~0u >> (31 - bh)) & (~0u << bl);
        unsigned int paint = m & undone;
        undone &= ~m;
        float col = st.w;
        while (paint) {
            int j = __builtin_ctz(paint);
            paint &= paint - 1;
            crow[c0i + j] = col;
        }
    }
    __syncthreads();

    // ---- Phase D: separable sliding 3x3 blur + (1 - x), coalesced float2 store ----
    const float A    = 0.13533528323661270f;                  // e^-2
    const double Ad  = 0.13533528323661270;
    const float INVS = (float)(1.0 / ((1.0 + 2.0 * Ad) * (1.0 + 2.0 * Ad)));

    const int j0 = tid << 1;                                  // 0..510
    auto hrow = [&](int rr) -> float2 {
        const float* p = &canvas[rr * CSTR + j0];             // p[0] = col j0-1
        float x0 = p[0], x1 = p[1], x2 = p[2], x3 = p[3];
        return make_float2(x1 + A * (x0 + x2), x2 + A * (x1 + x3));
    };

    float2 hp = hrow(0);
    float2 hm = hrow(1);
    for (int orow = 0; orow < OUTH; ++orow) {
        float2 hn = hrow(orow + 2);
        int grow = R0 + orow;
        if (grow < W) {
            float2 o;
            o.x = 1.0f - (hm.x + A * (hp.x + hn.x)) * INVS;
            o.y = 1.0f - (hm.y + A * (hp.y + hn.y)) * INVS;
            *reinterpret_cast<float2*>(&out[((size_t)b * W + grow) * W + j0]) = o;
        }
        hp = hm; hm = hn;
    }
}

extern "C" void kernel_launch(void* const* d_in, const int* in_sizes, int n_in,
                              void* d_out, int out_size, void* d_ws, size_t ws_size,
                              hipStream_t stream) {
    const float* strokes = (const float*)d_in[0];
    float* out = (float*)d_out;
    int B = in_sizes[0] / 10;
    dim3 grid(NTILE, B);
    qbc_kernel<<<grid, dim3(256), 0, stream>>>(strokes, out, B);
}

// Round 6
// 168.019 us; speedup vs baseline: 1.4798x; 1.3890x over previous
//
#include <hip/hip_runtime.h>

#define W      512
#define NSTEP  100
#define OUTH   14                  // output rows per tile
#define RROWS  16                  // rasterized rows = OUTH + 2 halo
#define NTILE  37                  // ceil(512 / OUTH)
#define CSTRB  520                 // canvas byte row stride (col j at byte j+1)
#define SEGW   32                  // columns per painter thread

__global__ __launch_bounds__(256) void qbc_kernel(
    const float* __restrict__ strokes, float* __restrict__ out, int B)
{
    #pragma clang fp contract(off)   // match XLA per-op IEEE fp32 for the predicate

    const int b   = blockIdx.y;
    const int R0  = blockIdx.x * OUTH;   // output rows R0..R0+OUTH-1
    const int tid = threadIdx.x;

    __shared__ float4 steps[NSTEP];
    __shared__ float4 clist[NSTEP];
    __shared__ int    flags[NSTEP];
    __shared__ int    nlist;
    __shared__ float  colors[NSTEP + 1];         // colors[0] = background 0
    __shared__ int    ivl[NSTEP * RROWS];        // packed (jhi<<16)|(jlo&0xffff)
    __shared__ __align__(16) unsigned char cbytes[RROWS * CSTRB];  // u8 id canvas

    // ---- zero id-canvas (u8): 8320 B = 520 uint4 ----
    {
        uint4 z = make_uint4(0u, 0u, 0u, 0u);
        uint4* p = (uint4*)cbytes;
        for (int i = tid; i < (RROWS * CSTRB) / 16; i += 256) p[i] = z;
    }

    // ---- Phase A: per-step params (bit-exact mirror of reference fp32 ops) ----
    if (tid < NSTEP) {
        const float* s = strokes + b * 10;
        float P0x = s[0], P0y = s[1];
        float m1x = s[2], m1y = s[3];
        float P2x = s[4], P2y = s[5];
        float P1x = P0x + (P2x - P0x) * m1x;     // P1 = P0 + (P2-P0)*P1
        float P1y = P0y + (P2y - P0y) * m1y;
        float X0 = P0x * 511.0f + 0.5f;          // scale(v) = v*511 + 0.5
        float X1 = P1x * 511.0f + 0.5f;
        float X2 = P2x * 511.0f + 0.5f;
        float Y0 = P0y * 511.0f + 0.5f;
        float Y1 = P1y * 511.0f + 0.5f;
        float Y2 = P2y * 511.0f + 0.5f;
        float r0 = 1.0f + s[6] * 128.0f;
        float r2 = 1.0f + s[7] * 128.0f;
        float c0 = s[8], c2 = s[9];
        float tf = (float)tid * (1.0f / 99.0f);  // jnp.linspace fp32 semantics
        float mt = 1.0f - tf;
        float s0 = mt * mt;
        float s1 = (2.0f * mt) * tf;
        float s2 = tf * tf;
        float ex0 = X0 * s0, ex1 = X1 * s1, ex2 = X2 * s2;
        float X   = (ex0 + ex1) + ex2;
        float ey0 = Y0 * s0, ey1 = Y1 * s1, ey2 = Y2 * s2;
        float Y   = (ey0 + ey1) + ey2;
        float ra  = r0 * mt, rb = r2 * tf;
        float rt  = ra + rb;
        float r2t = rt * rt;
        float ca  = c0 * mt, cb = c2 * tf;
        float ct  = ca + cb;
        steps[tid] = make_float4(X, Y, r2t, ct);

        // cull vs raster row window [R0-1, R0+OUTH] (margin 4 >> fp slop)
        float lo_i = (float)(R0 - 1), hi_i = (float)(R0 + OUTH);
        float ci = fminf(fmaxf(X, lo_i), hi_i);
        float di = X - ci;
        flags[tid] = ((di * di) < (r2t + 4.0f)) ? 1 : 0;
    }
    __syncthreads();

    // ---- Phase B: order-preserving compaction (wave 0, ballot prefix) ----
    if (tid < 64) {
        bool f0 = flags[tid] != 0;
        unsigned long long m0 = __ballot(f0);
        int p0 = __popcll(m0 & ((1ull << tid) - 1ull));
        if (f0) { float4 v = steps[tid]; clist[p0] = v; colors[p0 + 1] = v.w; }
        int cnt = __popcll(m0);
        int t1 = 64 + tid;
        bool f1 = (t1 < NSTEP) && (flags[t1] != 0);
        unsigned long long m1 = __ballot(f1);
        int p1 = __popcll(m1 & ((1ull << tid) - 1ull));
        if (f1) { float4 v = steps[t1]; clist[cnt + p1] = v; colors[cnt + p1 + 1] = v.w; }
        if (tid == 0) { nlist = cnt + __popcll(m1); colors[0] = 0.0f; }
    }
    __syncthreads();
    const int n = nlist;

    // ---- Phase C1: per-(circle,row) exact interval, computed once, shared ----
    for (int job = tid; job < n * RROWS; job += 256) {
        int k   = job >> 4;                      // RROWS == 16
        int row = job & (RROWS - 1);
        float4 st = clist[k];
        float X = st.x, Y = st.y, r2 = st.z;
        int gi = R0 - 1 + row;
        float fi = (float)gi;
        float dx  = fi - X;
        float dxq = dx * dx;                     // exact fp32, reused by predicate
        int packed = 1;                          // jlo=1, jhi=0 -> empty
        float T = r2 - dxq;
        if (T >= -0.375f) {
            // exact fp32 predicate (bit-identical to reference)
            auto ehit = [&](int j) -> bool {
                float dy  = (float)j - Y;
                float dyq = dy * dy;
                float d2  = dxq + dyq;
                return d2 < r2;
            };
            float s_in = (T > 0.375f) ? sqrtf(T - 0.375f) : 0.0f;
            int gl = (int)ceilf (Y - s_in);
            int gh = (int)floorf(Y + s_in);
            int jlo, jhi; bool ok;
            if (gh - gl >= 4) {
                // boundary provably in {gl-1, gl, gl+1} / {gh-1, gh, gh+1}
                jlo = ehit(gl - 1) ? gl - 1 : (ehit(gl) ? gl : gl + 1);
                jhi = ehit(gh + 1) ? gh + 1 : (ehit(gh) ? gh : gh - 1);
                ok = true;
            } else {
                // tiny/tangent interval: exact-test the whole candidate window
                jlo = 1; jhi = 0; ok = false;
                for (int j = gl - 1; j <= gh + 1; ++j)
                    if (ehit(j)) { if (!ok) { jlo = j; ok = true; } jhi = j; }
            }
            if (ok) packed = (jhi << 16) | (jlo & 0xffff);
        }
        ivl[k * RROWS + row] = packed;
    }

    // painter thread layout: 16 rows x 16 segments of 32 cols (wave = 4 rows)
    const int seg = tid & 15;
    const int row = tid >> 4;
    const int gi  = R0 - 1 + row;
    const int c0i = seg * SEGW;
    unsigned char* crow = &cbytes[row * CSTRB + 1];   // col j at crow[j]
    __syncthreads();

    // ---- Phase C2: backward masked paint (tight loop, prefetched ivl) ----
    unsigned int undone = (gi >= 0 && gi < W) ? ~0u : 0u;
    int packed = (n > 0) ? ivl[(n - 1) * RROWS + row] : 1;
    for (int k = n - 1; k >= 0; --k) {
        if (__all(undone == 0u)) break;          // uniform early exit
        int nxt = (k > 0) ? ivl[(k - 1) * RROWS + row] : 1;  // prefetch
        if (undone) {
            int jlo = (int)(short)(packed & 0xffff);
            int jhi = packed >> 16;
            int lo = jlo > c0i ? jlo : c0i;
            int hi = jhi < c0i + SEGW - 1 ? jhi : c0i + SEGW - 1;
            if (lo <= hi) {
                unsigned int m = (~0u >> (31 - (hi - c0i))) & (~0u << (lo - c0i));
                unsigned int paint = m & undone;
                undone &= ~m;
                unsigned char id = (unsigned char)(k + 1);
                while (paint) {
                    int j = __builtin_ctz(paint);
                    paint &= paint - 1;
                    crow[c0i + j] = id;
                }
            }
        }
        packed = nxt;
    }
    __syncthreads();

    // ---- Phase D: separable sliding 3x3 blur + (1 - x), float2 store ----
    const float A    = 0.13533528323661270f;              // e^-2
    const double Ad  = 0.13533528323661270;
    const float INVS = (float)(1.0 / ((1.0 + 2.0 * Ad) * (1.0 + 2.0 * Ad)));

    const int j0 = tid << 1;                              // 0..510
    auto hrow = [&](int rr) -> float2 {
        const unsigned char* rb = &cbytes[rr * CSTRB];
        unsigned int w0 = *(const unsigned short*)(rb + j0);      // cols j0-1, j0
        unsigned int w1 = *(const unsigned short*)(rb + j0 + 2);  // cols j0+1, j0+2
        float x0 = colors[w0 & 0xffu];
        float x1 = colors[w0 >> 8];
        float x2 = colors[w1 & 0xffu];
        float x3 = colors[w1 >> 8];
        return make_float2(x1 + A * (x0 + x2), x2 + A * (x1 + x3));
    };

    float2 hp = hrow(0);
    float2 hm = hrow(1);
    for (int orow = 0; orow < OUTH; ++orow) {
        float2 hn = hrow(orow + 2);
        int grow = R0 + orow;
        if (grow < W) {
            float2 o;
            o.x = 1.0f - (hm.x + A * (hp.x + hn.x)) * INVS;
            o.y = 1.0f - (hm.y + A * (hp.y + hn.y)) * INVS;
            *reinterpret_cast<float2*>(&out[((size_t)b * W + grow) * W + j0]) = o;
        }
        hp = hm; hm = hn;
    }
}

extern "C" void kernel_launch(void* const* d_in, const int* in_sizes, int n_in,
                              void* d_out, int out_size, void* d_ws, size_t ws_size,
                              hipStream_t stream) {
    const float* strokes = (const float*)d_in[0];
    float* out = (float*)d_out;
    int B = in_sizes[0] / 10;
    dim3 grid(NTILE, B);
    qbc_kernel<<<grid, dim3(256), 0, stream>>>(strokes, out, B);
}